// Round 1
// baseline (414.588 us; speedup 1.0000x reference)
//
#include <hip/hip_runtime.h>
#include <cstdint>
#include <cstddef>

#define B_  64
#define D_  1024
#define S_  512
#define K_  100
#define KP_ 128
#define H_  2048
#define BS_ (B_*S_)   // 32768

// ---- workspace layout (float offsets) ----
static constexpr size_t OFF_TVN  = 0;                         // [1024][128] padded normalized topics
static constexpr size_t OFF_TPNT = 131072;                    // [100][32768] topic_prob_n transposed
static constexpr size_t OFF_HSUM = OFF_TPNT + (size_t)K_*BS_; // [64][2048] sum_s rec1
static constexpr size_t OFF_FEAT = OFF_HSUM + (size_t)B_*H_;  // [64][1024]
static constexpr size_t OFF_TOPK = OFF_FEAT + (size_t)B_*D_;  // [100] per-concept top16 sums
static constexpr size_t OFF_INTS = OFF_TOPK + 128;            // int region: cnt, bact[64], alist[32768]

// ---------------------------------------------------------------------------
__global__ __launch_bounds__(256) void zero_kernel(float* __restrict__ hsum,
                                                   int* __restrict__ ints)
{
    const int i = blockIdx.x * 256 + threadIdx.x;
    if (i < B_*H_) hsum[i] = 0.f;
    if (i < 65)    ints[i] = 0;
}

// ---------------------------------------------------------------------------
// Normalize topic_vector columns; write [1024][128] padded (cols 100..127 = 0).
__global__ __launch_bounds__(256) void tvnorm_kernel(const float* __restrict__ tv,
                                                     float* __restrict__ tvn)
{
    __shared__ float red[256];
    const int tid = threadIdx.x;
    const int k = blockIdx.x;                 // 0..127
    if (k >= K_) {
        for (int d = tid; d < D_; d += 256) tvn[d*KP_ + k] = 0.f;
        return;
    }
    float ss = 0.f;
    for (int d = tid; d < D_; d += 256) { float v = tv[d*K_ + k]; ss = fmaf(v, v, ss); }
    red[tid] = ss;
    __syncthreads();
    for (int s = 128; s > 0; s >>= 1) {
        if (tid < s) red[tid] += red[tid + s];
        __syncthreads();
    }
    const float inv = 1.0f / fmaxf(sqrtf(red[0]), 1e-12f);
    for (int d = tid; d < D_; d += 256) tvn[d*KP_ + k] = tv[d*K_ + k] * inv;
}

// ---------------------------------------------------------------------------
// Main kernel: topic_prob GEMM + row norms + mask + topic_prob_nn (-> d_out)
// + topic_prob_n transposed (-> ws) + active-row list.
// Grid: 512 blocks = 64 b x 8 s-tiles of 64. Block: 256 threads.
__global__ __launch_bounds__(256, 2) void gemm1_kernel(
    const float* __restrict__ f, const float* __restrict__ tvn,
    float* __restrict__ out_nn, float* __restrict__ tpnT,
    int* __restrict__ cnt, int* __restrict__ bact, int* __restrict__ alist)
{
    __shared__ __align__(16) float fs[2][32*64];    // f tile: 32 d x 64 s
    __shared__ __align__(16) float ts[2][32*128];   // topic tile: 32 d x 128 k
    __shared__ float red[16*64];
    __shared__ float ninv[64];
    __shared__ float rinv[64];

    const int tid = threadIdx.x;
    const int b   = blockIdx.x >> 3;
    const int s0  = (blockIdx.x & 7) << 6;

    // staging map: fj = float4 column (16 x 4 = 64 s), fd = d row (+16)
    const int fj = tid & 15;
    const int fd = tid >> 4;
    // compute map: 16 s-groups of 4 (broadcast within wave), 16 k-groups of 8
    const int trs = (tid & 15) << 2;
    const int tks = (tid >> 4) << 3;

    const float* fb = f + ((size_t)b * D_) * S_ + s0;

    float acc[4][8];
#pragma unroll
    for (int i = 0; i < 4; ++i)
#pragma unroll
        for (int j = 0; j < 8; ++j) acc[i][j] = 0.f;
    float nsq0 = 0.f, nsq1 = 0.f, nsq2 = 0.f, nsq3 = 0.f;

    float4 rf0, rf1, rt0, rt1, rt2, rt3;
    {   // prologue load (step 0)
        rf0 = *(const float4*)(fb + (size_t)fd * S_ + fj*4);
        rf1 = *(const float4*)(fb + (size_t)(fd+16) * S_ + fj*4);
        const float* tp = tvn;
        rt0 = *(const float4*)(tp + tid*4);
        rt1 = *(const float4*)(tp + (tid+256)*4);
        rt2 = *(const float4*)(tp + (tid+512)*4);
        rt3 = *(const float4*)(tp + (tid+768)*4);
    }

    for (int step = 0; step < 32; ++step) {
        float* fc = fs[step & 1];
        float* tc = ts[step & 1];
        __syncthreads();                       // everyone done reading this buffer
        *(float4*)&fc[fd*64 + fj*4]      = rf0;
        *(float4*)&fc[(fd+16)*64 + fj*4] = rf1;
        *(float4*)&tc[tid*4]       = rt0;
        *(float4*)&tc[(tid+256)*4] = rt1;
        *(float4*)&tc[(tid+512)*4] = rt2;
        *(float4*)&tc[(tid+768)*4] = rt3;
        // row-norm accumulation (free: values already in registers)
        nsq0 += rf0.x*rf0.x + rf1.x*rf1.x;
        nsq1 += rf0.y*rf0.y + rf1.y*rf1.y;
        nsq2 += rf0.z*rf0.z + rf1.z*rf1.z;
        nsq3 += rf0.w*rf0.w + rf1.w*rf1.w;
        if (step < 31) {                       // prefetch next tile into registers
            const int d0 = (step + 1) << 5;
            rf0 = *(const float4*)(fb + (size_t)(d0+fd) * S_ + fj*4);
            rf1 = *(const float4*)(fb + (size_t)(d0+fd+16) * S_ + fj*4);
            const float* tp = tvn + (size_t)d0 * KP_;
            rt0 = *(const float4*)(tp + tid*4);
            rt1 = *(const float4*)(tp + (tid+256)*4);
            rt2 = *(const float4*)(tp + (tid+512)*4);
            rt3 = *(const float4*)(tp + (tid+768)*4);
        }
        __syncthreads();                       // staging visible
#pragma unroll
        for (int di = 0; di < 32; ++di) {
            const float4 av = *(const float4*)&fc[di*64 + trs];
            const float4 w0 = *(const float4*)&tc[di*128 + tks];
            const float4 w1 = *(const float4*)&tc[di*128 + tks + 4];
            const float w[8] = {w0.x, w0.y, w0.z, w0.w, w1.x, w1.y, w1.z, w1.w};
#pragma unroll
            for (int j = 0; j < 8; ++j) {
                acc[0][j] = fmaf(av.x, w[j], acc[0][j]);
                acc[1][j] = fmaf(av.y, w[j], acc[1][j]);
                acc[2][j] = fmaf(av.z, w[j], acc[2][j]);
                acc[3][j] = fmaf(av.w, w[j], acc[3][j]);
            }
        }
    }

    // ---- epilogue ----
    // 1) row norms: reduce 16 d-groups
    red[fd*64 + fj*4 + 0] = nsq0;
    red[fd*64 + fj*4 + 1] = nsq1;
    red[fd*64 + fj*4 + 2] = nsq2;
    red[fd*64 + fj*4 + 3] = nsq3;
    __syncthreads();
    if (tid < 64) {
        float t = 0.f;
#pragma unroll
        for (int g = 0; g < 16; ++g) t += red[g*64 + tid];
        ninv[tid] = 1.0f / fmaxf(sqrtf(t), 1e-12f);
    }
    __syncthreads();

    const int bs0 = b * S_ + s0;
    const float inv0 = ninv[trs], inv1 = ninv[trs+1], inv2 = ninv[trs+2], inv3 = ninv[trs+3];
    float rowp0 = 0.f, rowp1 = 0.f, rowp2 = 0.f, rowp3 = 0.f;
#pragma unroll
    for (int j = 0; j < 8; ++j) {
        const float t0 = acc[0][j]*inv0, t1 = acc[1][j]*inv1,
                    t2 = acc[2][j]*inv2, t3 = acc[3][j]*inv3;
        acc[0][j] = (t0 > 0.3f) ? acc[0][j] : 0.f;   // topic_prob * mask, in place
        acc[1][j] = (t1 > 0.3f) ? acc[1][j] : 0.f;
        acc[2][j] = (t2 > 0.3f) ? acc[2][j] : 0.f;
        acc[3][j] = (t3 > 0.3f) ? acc[3][j] : 0.f;
        rowp0 += acc[0][j]; rowp1 += acc[1][j];
        rowp2 += acc[2][j]; rowp3 += acc[3][j];
        const int k = tks + j;
        if (k < K_) {                                // topic_prob_n transposed
            float4 v; v.x = t0; v.y = t1; v.z = t2; v.w = t3;
            *(float4*)&tpnT[(size_t)k*BS_ + bs0 + trs] = v;
        }
    }
    // 2) row sums: reduce 16 k-groups
    {
        const int tc2 = tid >> 4;
        red[tc2*64 + trs + 0] = rowp0;
        red[tc2*64 + trs + 1] = rowp1;
        red[tc2*64 + trs + 2] = rowp2;
        red[tc2*64 + trs + 3] = rowp3;
    }
    __syncthreads();
    if (tid < 64) {
        float t = 0.f;
#pragma unroll
        for (int g = 0; g < 16; ++g) t += red[g*64 + tid];
        rinv[tid] = 1.0f / (t + 0.001f);
        if (t > 0.f) {                               // row has any unmasked concept
            const int pos = atomicAdd(cnt, 1);
            alist[pos] = bs0 + tid;
            atomicAdd(&bact[b], 1);
        }
    }
    __syncthreads();
    const float r0 = rinv[trs], r1 = rinv[trs+1], r2 = rinv[trs+2], r3 = rinv[trs+3];
    float* o0 = out_nn + (size_t)(bs0 + trs) * K_;
#pragma unroll
    for (int j = 0; j < 8; ++j) {
        const int k = tks + j;
        if (k < K_) {
            o0[k]          = acc[0][j] * r0;
            o0[K_ + k]     = acc[1][j] * r1;
            o0[2*K_ + k]   = acc[2][j] * r2;
            o0[3*K_ + k]   = acc[3][j] * r3;
        }
    }
}

// ---------------------------------------------------------------------------
// Sparse rec1 accumulation: only rows with any active concept contribute.
__global__ __launch_bounds__(256) void gemm2_sparse(
    const float* __restrict__ nn, const float* __restrict__ W1,
    float* __restrict__ hsum, const int* __restrict__ cnt, const int* __restrict__ alist)
{
    __shared__ float nl[K_];
    const int n = *cnt;
    for (int idx = blockIdx.x; idx < n; idx += gridDim.x) {
        const int bs = alist[idx];
        const int b  = bs >> 9;
        __syncthreads();
        if (threadIdx.x < K_) nl[threadIdx.x] = nn[(size_t)bs*K_ + threadIdx.x];
        __syncthreads();
        for (int h = threadIdx.x; h < H_; h += 256) {
            float a = 0.f;
#pragma unroll 4
            for (int k = 0; k < K_; ++k) a = fmaf(nl[k], W1[k*H_ + h], a);
            atomicAdd(&hsum[(size_t)b*H_ + h], fmaxf(a, 0.f));
        }
    }
}

// ---------------------------------------------------------------------------
// feat[b][d] = (hsum[b] . W2[:,d]) / S    (skip W2 read when batch inactive)
__global__ __launch_bounds__(256) void gemm3_feat(
    const float* __restrict__ hsum, const float* __restrict__ W2,
    const int* __restrict__ bact, float* __restrict__ feat)
{
    __shared__ float hl[H_];
    const int b = blockIdx.x >> 2;
    const int d = ((blockIdx.x & 3) << 8) + threadIdx.x;
    if (bact[b] == 0) { feat[b*D_ + d] = 0.f; return; }   // block-uniform branch
    for (int h = threadIdx.x; h < H_; h += 256) hl[h] = hsum[(size_t)b*H_ + h];
    __syncthreads();
    float a = 0.f;
    for (int h = 0; h < H_; ++h) a = fmaf(hl[h], W2[(size_t)h*D_ + d], a);
    feat[b*D_ + d] = a * (1.0f/512.0f);
}

// ---------------------------------------------------------------------------
// Per-concept top-16 sum: per-thread register top16 (static branchless insert)
// + LDS tournament merge of 256x16 candidates.
__global__ __launch_bounds__(256) void topk_kernel(const float* __restrict__ tpnT,
                                                   float* __restrict__ topks)
{
    __shared__ float cand[4096];
    __shared__ float rv[256];
    __shared__ int   ri[256];
    const int tid = threadIdx.x;
    const int k = blockIdx.x;
    const float* col = tpnT + (size_t)k * BS_;
    float lst[16];
#pragma unroll
    for (int q = 0; q < 16; ++q) lst[q] = -3.4e38f;
    for (int i = tid; i < BS_; i += 256) {
        const float v = col[i];
        if (v > lst[0]) {
            float nl[16];
#pragma unroll
            for (int q = 0; q < 16; ++q) {
                const bool sh = (q < 15) ? (lst[q+1] < v) : false;
                nl[q] = sh ? lst[q+1] : ((lst[q] < v) ? v : lst[q]);
            }
#pragma unroll
            for (int q = 0; q < 16; ++q) lst[q] = nl[q];
        }
    }
#pragma unroll
    for (int q = 0; q < 16; ++q) cand[tid*16 + q] = lst[q];
    __syncthreads();
    float sum = 0.f;
    for (int r = 0; r < 16; ++r) {
        float m = -3.4e38f; int mi = 0;
#pragma unroll
        for (int q = 0; q < 16; ++q) {
            const float v = cand[tid*16 + q];
            if (v > m) { m = v; mi = q; }
        }
        rv[tid] = m; ri[tid] = tid;
        __syncthreads();
        for (int s = 128; s > 0; s >>= 1) {
            if (tid < s && rv[tid+s] > rv[tid]) { rv[tid] = rv[tid+s]; ri[tid] = ri[tid+s]; }
            __syncthreads();
        }
        sum += rv[0];
        if (tid == ri[0]) cand[tid*16 + mi] = -3.4e38f;
        __syncthreads();
    }
    if (tid == 0) topks[k] = sum;
}

// ---------------------------------------------------------------------------
// pred + scalars.
__global__ __launch_bounds__(256) void final_kernel(
    const float* __restrict__ feat, const float* __restrict__ Wc, const float* __restrict__ bc,
    const float* __restrict__ tvn, const float* __restrict__ topks, float* __restrict__ out)
{
    __shared__ float red[256];
    const int tid = threadIdx.x;
    // concept_far = (||sum_k tvn_col||^2 - K) / K^2
    float part = 0.f;
    for (int d = tid; d < D_; d += 256) {
        float s = 0.f;
        for (int k = 0; k < K_; ++k) s += tvn[d*KP_ + k];
        part = fmaf(s, s, part);
    }
    red[tid] = part;
    __syncthreads();
    for (int s = 128; s > 0; s >>= 1) {
        if (tid < s) red[tid] += red[tid+s];
        __syncthreads();
    }
    if (tid == 0) out[130] = (red[0] - (float)K_) / ((float)K_ * (float)K_);
    __syncthreads();
    // concept_sim = -mean(topk values)
    red[tid] = (tid < K_) ? topks[tid] : 0.f;
    __syncthreads();
    for (int s = 128; s > 0; s >>= 1) {
        if (tid < s) red[tid] += red[tid+s];
        __syncthreads();
    }
    if (tid == 0) out[129] = -red[0] / (float)(K_ * 16);
    if (tid == 1) out[128] = 0.f;
    // pred = feat @ W_cls + b_cls
    if (tid < 128) {
        const int b = tid >> 1, c = tid & 1;
        float a = bc[c];
        for (int d = 0; d < D_; ++d) a = fmaf(feat[b*D_ + d], Wc[d*2 + c], a);
        out[tid] = a;
    }
}

// ---------------------------------------------------------------------------
extern "C" void kernel_launch(void* const* d_in, const int* in_sizes, int n_in,
                              void* d_out, int out_size, void* d_ws, size_t ws_size,
                              hipStream_t stream)
{
    (void)in_sizes; (void)n_in; (void)out_size; (void)ws_size;
    const float* f   = (const float*)d_in[0];
    const float* tv  = (const float*)d_in[1];
    const float* W1  = (const float*)d_in[2];
    const float* W2  = (const float*)d_in[3];
    const float* Wc  = (const float*)d_in[4];
    const float* bc  = (const float*)d_in[5];
    float* out  = (float*)d_out;
    float* ws   = (float*)d_ws;

    float* tvn   = ws + OFF_TVN;
    float* tpnT  = ws + OFF_TPNT;
    float* hsum  = ws + OFF_HSUM;
    float* feat  = ws + OFF_FEAT;
    float* topks = ws + OFF_TOPK;
    int*   ints  = (int*)(ws + OFF_INTS);
    int* cnt   = ints;
    int* bact  = ints + 1;
    int* alist = ints + 65;
    float* out_nn = out + 131;

    hipLaunchKernelGGL(zero_kernel,  dim3(512), dim3(256), 0, stream, hsum, ints);
    hipLaunchKernelGGL(tvnorm_kernel, dim3(KP_), dim3(256), 0, stream, tv, tvn);
    hipLaunchKernelGGL(gemm1_kernel, dim3(512), dim3(256), 0, stream,
                       f, tvn, out_nn, tpnT, cnt, bact, alist);
    hipLaunchKernelGGL(gemm2_sparse, dim3(128), dim3(256), 0, stream,
                       out_nn, W1, hsum, cnt, alist);
    hipLaunchKernelGGL(gemm3_feat,   dim3(256), dim3(256), 0, stream, hsum, W2, bact, feat);
    hipLaunchKernelGGL(topk_kernel,  dim3(K_),  dim3(256), 0, stream, tpnT, topks);
    hipLaunchKernelGGL(final_kernel, dim3(1),   dim3(256), 0, stream, feat, Wc, bc, tvn, topks, out);
}